// Round 1
// baseline (1097.105 us; speedup 1.0000x reference)
//
#include <hip/hip_runtime.h>
#include <hip/hip_bf16.h>
#include <math.h>

// Problem constants (validated against in_sizes at launch)
#define FEAT 64

// ---------------------------------------------------------------------------
// CSR build: degree count -> exclusive scan -> scatter
// ---------------------------------------------------------------------------
__global__ void zero_kernel(int* __restrict__ p, int n) {
    int i = blockIdx.x * blockDim.x + threadIdx.x;
    if (i < n) p[i] = 0;
}

__global__ void count_kernel(const int* __restrict__ dst, int* __restrict__ deg, int nE) {
    int i = blockIdx.x * blockDim.x + threadIdx.x;
    if (i < nE) atomicAdd(&deg[dst[i]], 1);
}

// single-block exclusive scan of deg[0..n) -> off[0..n]
__global__ __launch_bounds__(1024) void scan_kernel(const int* __restrict__ deg,
                                                    int* __restrict__ off, int n) {
    __shared__ int partial[1024];
    int tid = threadIdx.x;
    int chunk = (n + 1023) / 1024;
    int begin = tid * chunk;
    int end   = begin + chunk; if (end > n) end = n; if (begin > n) begin = n;
    int sum = 0;
    for (int i = begin; i < end; ++i) sum += deg[i];
    partial[tid] = sum;
    __syncthreads();
    for (int d = 1; d < 1024; d <<= 1) {
        int v = (tid >= d) ? partial[tid - d] : 0;
        __syncthreads();
        partial[tid] += v;
        __syncthreads();
    }
    int run = (tid == 0) ? 0 : partial[tid - 1];
    for (int i = begin; i < end; ++i) { off[i] = run; run += deg[i]; }
    if (tid == 1023) off[n] = run;   // == E
}

__global__ void scatter_kernel(const int* __restrict__ src, const int* __restrict__ dst,
                               const int* __restrict__ off, int* __restrict__ cursor,
                               int* __restrict__ csr_src, int nE) {
    int i = blockIdx.x * blockDim.x + threadIdx.x;
    if (i < nE) {
        int d = dst[i];
        int p = atomicAdd(&cursor[d], 1);
        csr_src[off[d] + p] = src[i];
    }
}

// ---------------------------------------------------------------------------
// Max-aggregation gather: one wave per node, lane = feature
// ---------------------------------------------------------------------------
__global__ __launch_bounds__(256) void agg_kernel(const float* __restrict__ h,
                                                  const int* __restrict__ off,
                                                  const int* __restrict__ csr_src,
                                                  float* __restrict__ agg, int nNodes) {
    int lane = threadIdx.x & 63;
    int wave = threadIdx.x >> 6;
    int stride = gridDim.x * 4;
    for (int n = blockIdx.x * 4 + wave; n < nNodes; n += stride) {
        int e0 = off[n], e1 = off[n + 1];
        float acc = -INFINITY;
        for (int e = e0; e < e1; ++e) {
            int s = csr_src[e];
            acc = fmaxf(acc, h[(size_t)s * FEAT + lane]);
        }
        agg[(size_t)n * FEAT + lane] = (e1 > e0) ? acc : 0.0f;
    }
}

// ---------------------------------------------------------------------------
// Node transform: out = relu(agg @ Wl^T + h @ (Wr+Ws)^T + (bl+bs))
// Weights kept in registers: lane f holds column f of both effective matrices.
// ---------------------------------------------------------------------------
__global__ __launch_bounds__(256) void transform_kernel(const float* __restrict__ h,
                                                        const float* __restrict__ agg,
                                                        const float* __restrict__ Wl,
                                                        const float* __restrict__ bl,
                                                        const float* __restrict__ Wr,
                                                        const float* __restrict__ Ws,
                                                        const float* __restrict__ bs,
                                                        float* __restrict__ out, int nNodes) {
    int lane = threadIdx.x & 63;
    int wave = threadIdx.x >> 6;

    // lane f needs Wl[f][k] and (Wr+Ws)[f][k] for all k -> 128 VGPRs
    float wl[FEAT], wc[FEAT];
#pragma unroll
    for (int k = 0; k < FEAT; k += 4) {
        float4 a = *(const float4*)&Wl[lane * FEAT + k];
        float4 r = *(const float4*)&Wr[lane * FEAT + k];
        float4 s = *(const float4*)&Ws[lane * FEAT + k];
        wl[k] = a.x; wl[k + 1] = a.y; wl[k + 2] = a.z; wl[k + 3] = a.w;
        wc[k] = r.x + s.x; wc[k + 1] = r.y + s.y; wc[k + 2] = r.z + s.z; wc[k + 3] = r.w + s.w;
    }
    float bias = bl[lane] + bs[lane];

    int stride = gridDim.x * 4;
    for (int n = blockIdx.x * 4 + wave; n < nNodes; n += stride) {
        float av = agg[(size_t)n * FEAT + lane];
        float hv = h[(size_t)n * FEAT + lane];
        float acc = bias;
#pragma unroll
        for (int k = 0; k < FEAT; ++k) {
            acc = fmaf(__shfl(av, k), wl[k], acc);   // readlane -> SGPR operand
            acc = fmaf(__shfl(hv, k), wc[k], acc);
        }
        out[(size_t)n * FEAT + lane] = fmaxf(acc, 0.0f);
    }
}

// ---------------------------------------------------------------------------
extern "C" void kernel_launch(void* const* d_in, const int* in_sizes, int n_in,
                              void* d_out, int out_size, void* d_ws, size_t ws_size,
                              hipStream_t stream) {
    const float* x   = (const float*)d_in[0];
    const int* eidx  = (const int*)d_in[1];
    const int N  = in_sizes[0] / FEAT;     // 100000
    const int E  = in_sizes[1] / 2;        // 1600000
    const int* src = eidx;
    const int* dst = eidx + E;

    // per-layer weights: d_in[2 + 5*li + {0..4}] = Wl, bl, Wr, Ws, bs
    const float* Wl[3]; const float* bl[3]; const float* Wr[3];
    const float* Ws[3]; const float* bs[3];
    for (int li = 0; li < 3; ++li) {
        Wl[li] = (const float*)d_in[2 + 5 * li + 0];
        bl[li] = (const float*)d_in[2 + 5 * li + 1];
        Wr[li] = (const float*)d_in[2 + 5 * li + 2];
        Ws[li] = (const float*)d_in[2 + 5 * li + 3];
        bs[li] = (const float*)d_in[2 + 5 * li + 4];
    }

    // workspace carve (256B aligned)
    auto align256 = [](size_t v) { return (v + 255) & ~(size_t)255; };
    char* ws = (char*)d_ws;
    int* off      = (int*)ws;  ws += align256((size_t)(N + 1) * 4);
    int* cursor   = (int*)ws;  ws += align256((size_t)N * 4);
    int* csr_src  = (int*)ws;  ws += align256((size_t)E * 4);
    float* aggbuf = (float*)ws; ws += align256((size_t)N * FEAT * 4);
    float* h1     = (float*)ws; ws += align256((size_t)N * FEAT * 4);
    float* h2     = (float*)ws; ws += align256((size_t)N * FEAT * 4);

    const int TB = 256;
    int eBlocks = (E + TB - 1) / TB;
    int nBlocks = (N + TB - 1) / TB;

    // ---- CSR build (graph is identical for all 3 layers) ----
    zero_kernel<<<nBlocks, TB, 0, stream>>>(cursor, N);
    count_kernel<<<eBlocks, TB, 0, stream>>>(dst, cursor, E);
    scan_kernel<<<1, 1024, 0, stream>>>(cursor, off, N);
    zero_kernel<<<nBlocks, TB, 0, stream>>>(cursor, N);
    scatter_kernel<<<eBlocks, TB, 0, stream>>>(src, dst, off, cursor, csr_src, E);

    const int AGG_GRID = 2048;   // 8192 waves, grid-stride
    const int TRF_GRID = 2048;

    // ---- layer 0: x -> h1 ----
    agg_kernel<<<AGG_GRID, TB, 0, stream>>>(x, off, csr_src, aggbuf, N);
    transform_kernel<<<TRF_GRID, TB, 0, stream>>>(x, aggbuf, Wl[0], bl[0], Wr[0], Ws[0], bs[0], h1, N);
    // ---- layer 1: h1 -> h2 ----
    agg_kernel<<<AGG_GRID, TB, 0, stream>>>(h1, off, csr_src, aggbuf, N);
    transform_kernel<<<TRF_GRID, TB, 0, stream>>>(h1, aggbuf, Wl[1], bl[1], Wr[1], Ws[1], bs[1], h2, N);
    // ---- layer 2: h2 -> d_out ----
    agg_kernel<<<AGG_GRID, TB, 0, stream>>>(h2, off, csr_src, aggbuf, N);
    transform_kernel<<<TRF_GRID, TB, 0, stream>>>(h2, aggbuf, Wl[2], bl[2], Wr[2], Ws[2], bs[2],
                                                  (float*)d_out, N);
}

// Round 2
// 852.884 us; speedup vs baseline: 1.2863x; 1.2863x over previous
//
#include <hip/hip_runtime.h>
#include <hip/hip_bf16.h>
#include <math.h>

#define FEAT 64

// ---------------------------------------------------------------------------
// CSR build: degree count -> exclusive scan -> scatter
// ---------------------------------------------------------------------------
__global__ void zero_kernel(int* __restrict__ p, int n) {
    int i = blockIdx.x * blockDim.x + threadIdx.x;
    if (i < n) p[i] = 0;
}

__global__ void count_kernel(const int* __restrict__ dst, int* __restrict__ deg, int nE) {
    int i = blockIdx.x * blockDim.x + threadIdx.x;
    if (i < nE) atomicAdd(&deg[dst[i]], 1);
}

// single-block exclusive scan of deg[0..n) -> off[0..n]
__global__ __launch_bounds__(1024) void scan_kernel(const int* __restrict__ deg,
                                                    int* __restrict__ off, int n) {
    __shared__ int partial[1024];
    int tid = threadIdx.x;
    int chunk = (n + 1023) / 1024;
    int begin = tid * chunk;
    int end   = begin + chunk; if (end > n) end = n; if (begin > n) begin = n;
    int sum = 0;
    for (int i = begin; i < end; ++i) sum += deg[i];
    partial[tid] = sum;
    __syncthreads();
    for (int d = 1; d < 1024; d <<= 1) {
        int v = (tid >= d) ? partial[tid - d] : 0;
        __syncthreads();
        partial[tid] += v;
        __syncthreads();
    }
    int run = (tid == 0) ? 0 : partial[tid - 1];
    for (int i = begin; i < end; ++i) { off[i] = run; run += deg[i]; }
    if (tid == 1023) off[n] = run;
}

__global__ void scatter_kernel(const int* __restrict__ src, const int* __restrict__ dst,
                               const int* __restrict__ off, int* __restrict__ cursor,
                               int* __restrict__ csr_src, int nE) {
    int i = blockIdx.x * blockDim.x + threadIdx.x;
    if (i < nE) {
        int d = dst[i];
        int p = atomicAdd(&cursor[d], 1);
        csr_src[off[d] + p] = src[i];
    }
}

// ---------------------------------------------------------------------------
// Max-aggregation: one wave per node; 16 lanes x float4 per row, 4 edge slots
// per wave, unrolled x2 -> 2 outstanding 1 KiB loads per wave.
// ---------------------------------------------------------------------------
__device__ __forceinline__ float4 max4(float4 a, float4 b) {
    return make_float4(fmaxf(a.x, b.x), fmaxf(a.y, b.y), fmaxf(a.z, b.z), fmaxf(a.w, b.w));
}

__global__ __launch_bounds__(256) void agg_kernel(const float* __restrict__ h,
                                                  const int* __restrict__ off,
                                                  const int* __restrict__ csr_src,
                                                  float* __restrict__ agg, int nNodes) {
    int lane = threadIdx.x & 63;
    int g    = lane >> 4;    // edge slot 0..3
    int q    = lane & 15;    // feature quartet: features 4q..4q+3
    int wave = threadIdx.x >> 6;
    int stride = gridDim.x * 4;
    const float NEG = -INFINITY;

    for (int n = blockIdx.x * 4 + wave; n < nNodes; n += stride) {
        int e0 = off[n], e1 = off[n + 1];
        float4 acc0 = make_float4(NEG, NEG, NEG, NEG);
        float4 acc1 = acc0;
        int e = e0 + g;
        // 8 edges per iteration across the wave (2 per lane-group)
        for (; e + 4 < e1; e += 8) {
            int s0 = csr_src[e];
            int s1 = csr_src[e + 4];
            float4 v0 = *(const float4*)&h[(size_t)s0 * FEAT + q * 4];
            float4 v1 = *(const float4*)&h[(size_t)s1 * FEAT + q * 4];
            acc0 = max4(acc0, v0);
            acc1 = max4(acc1, v1);
        }
        if (e < e1) {
            int s0 = csr_src[e];
            float4 v0 = *(const float4*)&h[(size_t)s0 * FEAT + q * 4];
            acc0 = max4(acc0, v0);
        }
        float4 acc = max4(acc0, acc1);

        // reduce across the 4 edge-slot groups (lanes q, q+16, q+32, q+48)
        float4 t;
        t.x = __shfl_xor(acc.x, 16); t.y = __shfl_xor(acc.y, 16);
        t.z = __shfl_xor(acc.z, 16); t.w = __shfl_xor(acc.w, 16);
        acc = max4(acc, t);
        t.x = __shfl_xor(acc.x, 32); t.y = __shfl_xor(acc.y, 32);
        t.z = __shfl_xor(acc.z, 32); t.w = __shfl_xor(acc.w, 32);
        acc = max4(acc, t);

        if (e1 == e0) acc = make_float4(0.f, 0.f, 0.f, 0.f);  // empty segment -> 0
        if (g == 0)
            *(float4*)&agg[(size_t)n * FEAT + q * 4] = acc;
    }
}

// ---------------------------------------------------------------------------
// Node transform: out = relu(agg @ Wl^T + h @ (Wr+Ws)^T + (bl+bs))
// lane = output feature; rows read as wave-uniform scalar loads (SMEM pipe);
// 4 accumulators break the FMA dependency chain.
// ---------------------------------------------------------------------------
__global__ __launch_bounds__(256) void transform_kernel(const float* __restrict__ h,
                                                        const float* __restrict__ agg,
                                                        const float* __restrict__ Wl,
                                                        const float* __restrict__ bl,
                                                        const float* __restrict__ Wr,
                                                        const float* __restrict__ Ws,
                                                        const float* __restrict__ bs,
                                                        float* __restrict__ out, int nNodes) {
    int lane = threadIdx.x & 63;
    int wave = threadIdx.x >> 6;

    float wl[FEAT], wc[FEAT];
#pragma unroll
    for (int k = 0; k < FEAT; k += 4) {
        float4 a = *(const float4*)&Wl[lane * FEAT + k];
        float4 r = *(const float4*)&Wr[lane * FEAT + k];
        float4 s = *(const float4*)&Ws[lane * FEAT + k];
        wl[k] = a.x; wl[k + 1] = a.y; wl[k + 2] = a.z; wl[k + 3] = a.w;
        wc[k] = r.x + s.x; wc[k + 1] = r.y + s.y; wc[k + 2] = r.z + s.z; wc[k + 3] = r.w + s.w;
    }
    float bias = bl[lane] + bs[lane];

    int stride = gridDim.x * 4;
    for (int n0 = blockIdx.x * 4 + wave; n0 < nNodes; n0 += stride) {
        int n = __builtin_amdgcn_readfirstlane(n0);          // wave-uniform -> s_load rows
        const float* __restrict__ ar = agg + (size_t)n * FEAT;
        const float* __restrict__ hr = h + (size_t)n * FEAT;
        float a0 = bias, a1 = 0.f, a2 = 0.f, a3 = 0.f;
#pragma unroll
        for (int k = 0; k < FEAT; k += 2) {
            a0 = fmaf(ar[k],     wl[k],     a0);
            a1 = fmaf(ar[k + 1], wl[k + 1], a1);
            a2 = fmaf(hr[k],     wc[k],     a2);
            a3 = fmaf(hr[k + 1], wc[k + 1], a3);
        }
        out[(size_t)n * FEAT + lane] = fmaxf((a0 + a1) + (a2 + a3), 0.0f);
    }
}

// ---------------------------------------------------------------------------
extern "C" void kernel_launch(void* const* d_in, const int* in_sizes, int n_in,
                              void* d_out, int out_size, void* d_ws, size_t ws_size,
                              hipStream_t stream) {
    const float* x   = (const float*)d_in[0];
    const int* eidx  = (const int*)d_in[1];
    const int N  = in_sizes[0] / FEAT;
    const int E  = in_sizes[1] / 2;
    const int* src = eidx;
    const int* dst = eidx + E;

    const float* Wl[3]; const float* bl[3]; const float* Wr[3];
    const float* Ws[3]; const float* bs[3];
    for (int li = 0; li < 3; ++li) {
        Wl[li] = (const float*)d_in[2 + 5 * li + 0];
        bl[li] = (const float*)d_in[2 + 5 * li + 1];
        Wr[li] = (const float*)d_in[2 + 5 * li + 2];
        Ws[li] = (const float*)d_in[2 + 5 * li + 3];
        bs[li] = (const float*)d_in[2 + 5 * li + 4];
    }

    auto align256 = [](size_t v) { return (v + 255) & ~(size_t)255; };
    char* ws = (char*)d_ws;
    int* off      = (int*)ws;  ws += align256((size_t)(N + 1) * 4);
    int* cursor   = (int*)ws;  ws += align256((size_t)N * 4);
    int* csr_src  = (int*)ws;  ws += align256((size_t)E * 4);
    float* aggbuf = (float*)ws; ws += align256((size_t)N * FEAT * 4);
    float* h1     = (float*)ws; ws += align256((size_t)N * FEAT * 4);
    float* h2     = (float*)ws; ws += align256((size_t)N * FEAT * 4);

    const int TB = 256;
    int eBlocks = (E + TB - 1) / TB;
    int nBlocks = (N + TB - 1) / TB;

    // ---- CSR build ----
    zero_kernel<<<nBlocks, TB, 0, stream>>>(cursor, N);
    count_kernel<<<eBlocks, TB, 0, stream>>>(dst, cursor, E);
    scan_kernel<<<1, 1024, 0, stream>>>(cursor, off, N);
    zero_kernel<<<nBlocks, TB, 0, stream>>>(cursor, N);
    scatter_kernel<<<eBlocks, TB, 0, stream>>>(src, dst, off, cursor, csr_src, E);

    const int AGG_GRID = 2048;
    const int TRF_GRID = 2048;

    agg_kernel<<<AGG_GRID, TB, 0, stream>>>(x, off, csr_src, aggbuf, N);
    transform_kernel<<<TRF_GRID, TB, 0, stream>>>(x, aggbuf, Wl[0], bl[0], Wr[0], Ws[0], bs[0], h1, N);
    agg_kernel<<<AGG_GRID, TB, 0, stream>>>(h1, off, csr_src, aggbuf, N);
    transform_kernel<<<TRF_GRID, TB, 0, stream>>>(h1, aggbuf, Wl[1], bl[1], Wr[1], Ws[1], bs[1], h2, N);
    agg_kernel<<<AGG_GRID, TB, 0, stream>>>(h2, off, csr_src, aggbuf, N);
    transform_kernel<<<TRF_GRID, TB, 0, stream>>>(h2, aggbuf, Wl[2], bl[2], Wr[2], Ws[2], bs[2],
                                                  (float*)d_out, N);
}

// Round 3
// 708.449 us; speedup vs baseline: 1.5486x; 1.2039x over previous
//
#include <hip/hip_runtime.h>
#include <hip/hip_bf16.h>
#include <math.h>

#define FEAT 64
#define SCAN_CHUNK 2048   // elements per scan block (256 thr x 8)

// ---------------------------------------------------------------------------
// CSR build: degree count -> hierarchical exclusive scan -> scatter
// ---------------------------------------------------------------------------
__global__ void zero_kernel(int* __restrict__ p, int n) {
    int i = blockIdx.x * blockDim.x + threadIdx.x;
    if (i < n) p[i] = 0;
}

__global__ void count_kernel(const int* __restrict__ dst, int* __restrict__ deg, int nE) {
    int i = blockIdx.x * blockDim.x + threadIdx.x;
    if (i < nE) atomicAdd(&deg[dst[i]], 1);
}

// stage 1: per-block sums of 2048-elem chunks
__global__ __launch_bounds__(256) void scan_sum_kernel(const int* __restrict__ deg,
                                                       int* __restrict__ bsum, int n) {
    __shared__ int sdata[4];
    int base = blockIdx.x * SCAN_CHUNK;
    int sum = 0;
    for (int i = threadIdx.x; i < SCAN_CHUNK; i += 256) {
        int idx = base + i;
        if (idx < n) sum += deg[idx];
    }
    for (int d = 32; d > 0; d >>= 1) sum += __shfl_down(sum, d);
    if ((threadIdx.x & 63) == 0) sdata[threadIdx.x >> 6] = sum;
    __syncthreads();
    if (threadIdx.x == 0) bsum[blockIdx.x] = sdata[0] + sdata[1] + sdata[2] + sdata[3];
}

// stage 2: exclusive scan of block sums (nb <= 64) in one wave
__global__ void scan_block_kernel(const int* __restrict__ bsum, int* __restrict__ boff, int nb) {
    int tid = threadIdx.x;
    int own = (tid < nb) ? bsum[tid] : 0;
    int v = own;
    for (int d = 1; d < 64; d <<= 1) {
        int t = __shfl_up(v, d);
        if (tid >= d) v += t;
    }
    if (tid < nb) boff[tid] = v - own;   // exclusive
}

// stage 3: per-block local exclusive scan + global offset, write off[]
__global__ __launch_bounds__(256) void scan_write_kernel(const int* __restrict__ deg,
                                                         const int* __restrict__ boff,
                                                         int* __restrict__ off, int n, int E) {
    __shared__ int sw[8];
    int b = blockIdx.x;
    int t = threadIdx.x;
    int i0 = b * SCAN_CHUNK + t * 8;
    int local[8];
    int s = 0;
#pragma unroll
    for (int j = 0; j < 8; ++j) {
        int idx = i0 + j;
        local[j] = (idx < n) ? deg[idx] : 0;
        s += local[j];
    }
    int lane = t & 63, w = t >> 6;
    int inc = s;
    for (int d = 1; d < 64; d <<= 1) {
        int tt = __shfl_up(inc, d);
        if (lane >= d) inc += tt;
    }
    if (lane == 63) sw[w] = inc;
    __syncthreads();
    if (t == 0) { int r = 0; for (int k = 0; k < 4; ++k) { int v = sw[k]; sw[k] = r; r += v; } }
    __syncthreads();
    int texc = (inc - s) + sw[w] + boff[b];
#pragma unroll
    for (int j = 0; j < 8; ++j) {
        int idx = i0 + j;
        if (idx < n) off[idx] = texc;
        texc += local[j];
    }
    if (b == 0 && t == 0) off[n] = E;   // total degree == E (every edge has a dst)
}

__global__ void scatter_kernel(const int* __restrict__ src, const int* __restrict__ dst,
                               const int* __restrict__ off, int* __restrict__ cursor,
                               int* __restrict__ csr_src, int nE) {
    int i = blockIdx.x * blockDim.x + threadIdx.x;
    if (i < nE) {
        int d = dst[i];
        int p = atomicAdd(&cursor[d], 1);
        csr_src[off[d] + p] = src[i];
    }
}

// ---------------------------------------------------------------------------
// Max-aggregation: one 16-lane group per node (4 independent nodes per wave),
// inner loop unrolled x4 -> up to 16 row-loads in flight per wave.
// ---------------------------------------------------------------------------
__device__ __forceinline__ float4 max4(float4 a, float4 b) {
    return make_float4(fmaxf(a.x, b.x), fmaxf(a.y, b.y), fmaxf(a.z, b.z), fmaxf(a.w, b.w));
}

__global__ __launch_bounds__(256) void agg_kernel(const float* __restrict__ h,
                                                  const int* __restrict__ off,
                                                  const int* __restrict__ csr_src,
                                                  float* __restrict__ agg, int nNodes) {
    int gid = blockIdx.x * blockDim.x + threadIdx.x;
    int n = gid >> 4;          // node = global 16-lane group id
    int q = gid & 15;          // feature quartet
    if (n >= nNodes) return;

    int e0 = off[n], e1 = off[n + 1];
    const float NEG = -INFINITY;
    float4 acc0 = make_float4(NEG, NEG, NEG, NEG);
    float4 acc1 = acc0;
    int e = e0;
    for (; e + 4 <= e1; e += 4) {
        int s0 = csr_src[e], s1 = csr_src[e + 1], s2 = csr_src[e + 2], s3 = csr_src[e + 3];
        float4 v0 = *(const float4*)&h[(size_t)s0 * FEAT + q * 4];
        float4 v1 = *(const float4*)&h[(size_t)s1 * FEAT + q * 4];
        float4 v2 = *(const float4*)&h[(size_t)s2 * FEAT + q * 4];
        float4 v3 = *(const float4*)&h[(size_t)s3 * FEAT + q * 4];
        acc0 = max4(acc0, max4(v0, v1));
        acc1 = max4(acc1, max4(v2, v3));
    }
    for (; e < e1; ++e) {
        int s0 = csr_src[e];
        float4 v0 = *(const float4*)&h[(size_t)s0 * FEAT + q * 4];
        acc0 = max4(acc0, v0);
    }
    float4 acc = max4(acc0, acc1);
    if (e1 == e0) acc = make_float4(0.f, 0.f, 0.f, 0.f);
    *(float4*)&agg[(size_t)n * FEAT + q * 4] = acc;
}

// ---------------------------------------------------------------------------
// Node transform: out = relu(agg @ Wl^T + h @ (Wr+Ws)^T + (bl+bs))
// lane = output feature; rows read as wave-uniform scalar loads (SMEM pipe).
// ---------------------------------------------------------------------------
__global__ __launch_bounds__(256) void transform_kernel(const float* __restrict__ h,
                                                        const float* __restrict__ agg,
                                                        const float* __restrict__ Wl,
                                                        const float* __restrict__ bl,
                                                        const float* __restrict__ Wr,
                                                        const float* __restrict__ Ws,
                                                        const float* __restrict__ bs,
                                                        float* __restrict__ out, int nNodes) {
    int lane = threadIdx.x & 63;
    int wave = threadIdx.x >> 6;

    float wl[FEAT], wc[FEAT];
#pragma unroll
    for (int k = 0; k < FEAT; k += 4) {
        float4 a = *(const float4*)&Wl[lane * FEAT + k];
        float4 r = *(const float4*)&Wr[lane * FEAT + k];
        float4 s = *(const float4*)&Ws[lane * FEAT + k];
        wl[k] = a.x; wl[k + 1] = a.y; wl[k + 2] = a.z; wl[k + 3] = a.w;
        wc[k] = r.x + s.x; wc[k + 1] = r.y + s.y; wc[k + 2] = r.z + s.z; wc[k + 3] = r.w + s.w;
    }
    float bias = bl[lane] + bs[lane];

    int stride = gridDim.x * 4;
    for (int n0 = blockIdx.x * 4 + wave; n0 < nNodes; n0 += stride) {
        int n = __builtin_amdgcn_readfirstlane(n0);
        const float* __restrict__ ar = agg + (size_t)n * FEAT;
        const float* __restrict__ hr = h + (size_t)n * FEAT;
        float a0 = bias, a1 = 0.f, a2 = 0.f, a3 = 0.f;
#pragma unroll
        for (int k = 0; k < FEAT; k += 2) {
            a0 = fmaf(ar[k],     wl[k],     a0);
            a1 = fmaf(ar[k + 1], wl[k + 1], a1);
            a2 = fmaf(hr[k],     wc[k],     a2);
            a3 = fmaf(hr[k + 1], wc[k + 1], a3);
        }
        out[(size_t)n * FEAT + lane] = fmaxf((a0 + a1) + (a2 + a3), 0.0f);
    }
}

// ---------------------------------------------------------------------------
extern "C" void kernel_launch(void* const* d_in, const int* in_sizes, int n_in,
                              void* d_out, int out_size, void* d_ws, size_t ws_size,
                              hipStream_t stream) {
    const float* x   = (const float*)d_in[0];
    const int* eidx  = (const int*)d_in[1];
    const int N  = in_sizes[0] / FEAT;
    const int E  = in_sizes[1] / 2;
    const int* src = eidx;
    const int* dst = eidx + E;

    const float* Wl[3]; const float* bl[3]; const float* Wr[3];
    const float* Ws[3]; const float* bs[3];
    for (int li = 0; li < 3; ++li) {
        Wl[li] = (const float*)d_in[2 + 5 * li + 0];
        bl[li] = (const float*)d_in[2 + 5 * li + 1];
        Wr[li] = (const float*)d_in[2 + 5 * li + 2];
        Ws[li] = (const float*)d_in[2 + 5 * li + 3];
        bs[li] = (const float*)d_in[2 + 5 * li + 4];
    }

    auto align256 = [](size_t v) { return (v + 255) & ~(size_t)255; };
    char* ws = (char*)d_ws;
    int* off      = (int*)ws;  ws += align256((size_t)(N + 1) * 4);
    int* cursor   = (int*)ws;  ws += align256((size_t)N * 4);
    int* bsum     = (int*)ws;  ws += align256(64 * 4);
    int* boff     = (int*)ws;  ws += align256(64 * 4);
    int* csr_src  = (int*)ws;  ws += align256((size_t)E * 4);
    float* aggbuf = (float*)ws; ws += align256((size_t)N * FEAT * 4);
    float* h1     = (float*)ws; ws += align256((size_t)N * FEAT * 4);
    float* h2     = (float*)ws; ws += align256((size_t)N * FEAT * 4);

    const int TB = 256;
    int eBlocks = (E + TB - 1) / TB;
    int nBlocks = (N + TB - 1) / TB;
    int nb = (N + SCAN_CHUNK - 1) / SCAN_CHUNK;   // <= 64 for N <= 131072

    // ---- CSR build ----
    zero_kernel<<<nBlocks, TB, 0, stream>>>(cursor, N);
    count_kernel<<<eBlocks, TB, 0, stream>>>(dst, cursor, E);
    scan_sum_kernel<<<nb, TB, 0, stream>>>(cursor, bsum, N);
    scan_block_kernel<<<1, 64, 0, stream>>>(bsum, boff, nb);
    scan_write_kernel<<<nb, TB, 0, stream>>>(cursor, boff, off, N, E);
    zero_kernel<<<nBlocks, TB, 0, stream>>>(cursor, N);
    scatter_kernel<<<eBlocks, TB, 0, stream>>>(src, dst, off, cursor, csr_src, E);

    int aggBlocks = (N * 16 + TB - 1) / TB;   // one 16-lane group per node
    const int TRF_GRID = 2048;

    agg_kernel<<<aggBlocks, TB, 0, stream>>>(x, off, csr_src, aggbuf, N);
    transform_kernel<<<TRF_GRID, TB, 0, stream>>>(x, aggbuf, Wl[0], bl[0], Wr[0], Ws[0], bs[0], h1, N);
    agg_kernel<<<aggBlocks, TB, 0, stream>>>(h1, off, csr_src, aggbuf, N);
    transform_kernel<<<TRF_GRID, TB, 0, stream>>>(h1, aggbuf, Wl[1], bl[1], Wr[1], Ws[1], bs[1], h2, N);
    agg_kernel<<<aggBlocks, TB, 0, stream>>>(h2, off, csr_src, aggbuf, N);
    transform_kernel<<<TRF_GRID, TB, 0, stream>>>(h2, aggbuf, Wl[2], bl[2], Wr[2], Ws[2], bs[2],
                                                  (float*)d_out, N);
}